// Round 1
// baseline (2996.015 us; speedup 1.0000x reference)
//
#include <hip/hip_runtime.h>
#include <math.h>

// MambaBlock: B=8, T=2048, D_MODEL=1024, D_STATE=256, all fp32.
//
// Decomposition (ws layout, needs 176 MB of d_ws):
//   u   = x @ W_in + b_in                       [16384,256]   ws +   0 MB
//   u2  = u @ Bm                                [16384,256]   ws +  16 MB
//   h   = scan(tanh(h@A + u2_t))                [16384,256]   ws +  32 MB
//   big = u @ D^T  (+= h @ C^T later)           [16384,1024]  ws +  48 MB
//   g   = sigmoid(x @ W_gate + b_gate)          [16384,1024]  ws + 112 MB
//   ys  = g*big + (1-g)*x   (in-place into g)
//   out = ys @ W_out + b_out + x                [16384,1024]  d_out

enum { E_NONE = 0, E_BIAS = 1, E_SIG = 2, E_ACC = 3, E_BIASRES = 4 };

// 64x64 tile fp32 GEMM, BK=16, 256 threads, 4x4 accum per thread.
// BT: B stored [N,K] (we need B[k][n] = Bg[n*K+k]).
template <int EPI, bool BT>
__global__ __launch_bounds__(256) void gemm64(
    const float* __restrict__ Ag, const float* __restrict__ Bg,
    const float* __restrict__ bias, const float* __restrict__ res,
    float* Cg, int M, int N, int K)
{
    __shared__ float As[16][68];  // [k][m]
    __shared__ float Bs[16][68];  // [k][n]
    const int tid = threadIdx.x;
    const int m0 = blockIdx.y * 64, n0 = blockIdx.x * 64;
    const int tm = (tid >> 4) << 2;   // 0..60
    const int tn = (tid & 15) << 2;   // 0..60
    const int arow = tid >> 2;        // 0..63
    const int acol = (tid & 3) << 2;  // 0,4,8,12
    const int brow = tid >> 4;        // 0..15
    const int bcol = (tid & 15) << 2; // 0..60
    float acc[4][4] = {};

    for (int k0 = 0; k0 < K; k0 += 16) {
        float4 a4 = *(const float4*)(Ag + (size_t)(m0 + arow) * K + k0 + acol);
        As[acol + 0][arow] = a4.x; As[acol + 1][arow] = a4.y;
        As[acol + 2][arow] = a4.z; As[acol + 3][arow] = a4.w;
        if (!BT) {
            float4 b4 = *(const float4*)(Bg + (size_t)(k0 + brow) * N + n0 + bcol);
            Bs[brow][bcol + 0] = b4.x; Bs[brow][bcol + 1] = b4.y;
            Bs[brow][bcol + 2] = b4.z; Bs[brow][bcol + 3] = b4.w;
        } else {
            float4 b4 = *(const float4*)(Bg + (size_t)(n0 + arow) * K + k0 + acol);
            Bs[acol + 0][arow] = b4.x; Bs[acol + 1][arow] = b4.y;
            Bs[acol + 2][arow] = b4.z; Bs[acol + 3][arow] = b4.w;
        }
        __syncthreads();
#pragma unroll
        for (int k = 0; k < 16; ++k) {
            float am[4], bv[4];
#pragma unroll
            for (int i = 0; i < 4; ++i) am[i] = As[k][tm + i];
#pragma unroll
            for (int j = 0; j < 4; ++j) bv[j] = Bs[k][tn + j];
#pragma unroll
            for (int i = 0; i < 4; ++i)
#pragma unroll
                for (int j = 0; j < 4; ++j)
                    acc[i][j] = fmaf(am[i], bv[j], acc[i][j]);
        }
        __syncthreads();
    }

#pragma unroll
    for (int i = 0; i < 4; ++i) {
        const int m = m0 + tm + i, n = n0 + tn;
        const size_t idx = (size_t)m * N + n;
        float4 v = make_float4(acc[i][0], acc[i][1], acc[i][2], acc[i][3]);
        if (EPI == E_BIAS || EPI == E_SIG || EPI == E_BIASRES) {
            v.x += bias[n + 0]; v.y += bias[n + 1];
            v.z += bias[n + 2]; v.w += bias[n + 3];
        }
        if (EPI == E_SIG) {
            v.x = 1.f / (1.f + expf(-v.x)); v.y = 1.f / (1.f + expf(-v.y));
            v.z = 1.f / (1.f + expf(-v.z)); v.w = 1.f / (1.f + expf(-v.w));
        }
        if (EPI == E_ACC) {
            float4 c = *(const float4*)(Cg + idx);
            v.x += c.x; v.y += c.y; v.z += c.z; v.w += c.w;
        }
        if (EPI == E_BIASRES) {
            float4 r = *(const float4*)(res + idx);
            v.x += r.x; v.y += r.y; v.z += r.z; v.w += r.w;
        }
        *(float4*)(Cg + idx) = v;
    }
}

// Sequential recurrence h_t = tanh(h_{t-1} @ A + u2_t), one block per batch.
// 1024 threads: j = tid&255 (output col), kb = tid>>8 (k-quarter).
// A[k][j] for k in [kb*64, kb*64+64) lives in 64 VGPRs per thread.
// h broadcast from LDS via uniform-address float4 reads; u2 prefetched
// into double-buffered LDS 4 timesteps ahead (coalesced, latency hidden).
__global__ __launch_bounds__(1024) void scan_kernel(
    const float* __restrict__ Amat, const float* __restrict__ u2,
    float* __restrict__ hout)
{
    constexpr int T = 2048;
    __shared__ float h_lds[256];
    __shared__ float part[3][256];
    __shared__ float u_lds[2][1024];
    const int tid = threadIdx.x;
    const int j = tid & 255, kb = tid >> 8;
    const int b = blockIdx.x;
    const float* u2b = u2 + (size_t)b * T * 256;
    float* hb = hout + (size_t)b * T * 256;

    float a_reg[64];
#pragma unroll
    for (int i = 0; i < 64; ++i)
        a_reg[i] = Amat[(size_t)(kb * 64 + i) * 256 + j];

    if (tid < 256) h_lds[tid] = 0.f;
    u_lds[0][tid] = u2b[tid];  // timesteps 0..3
    __syncthreads();

    int buf = 0;
    for (int tg = 0; tg < T / 4; ++tg) {
        float pre = 0.f;
        if (tg + 1 < T / 4) pre = u2b[(size_t)(tg + 1) * 1024 + tid];
#pragma unroll
        for (int tt = 0; tt < 4; ++tt) {
            float acc = 0.f;
#pragma unroll
            for (int kq = 0; kq < 16; ++kq) {
                float4 hq = *(const float4*)&h_lds[kb * 64 + (kq << 2)];
                acc = fmaf(hq.x, a_reg[kq * 4 + 0], acc);
                acc = fmaf(hq.y, a_reg[kq * 4 + 1], acc);
                acc = fmaf(hq.z, a_reg[kq * 4 + 2], acc);
                acc = fmaf(hq.w, a_reg[kq * 4 + 3], acc);
            }
            if (kb) part[kb - 1][j] = acc;
            __syncthreads();
            if (!kb) {
                float s = acc + part[0][j] + part[1][j] + part[2][j]
                        + u_lds[buf][(tt << 8) + j];
                float hv = tanhf(s);
                h_lds[j] = hv;
                hb[(size_t)(tg * 4 + tt) * 256 + j] = hv;
            }
            __syncthreads();
        }
        u_lds[buf ^ 1][tid] = pre;
        buf ^= 1;
        __syncthreads();
    }
}

// ys = g*big + (1-g)*x, in-place into g (no __restrict__ on g/ys: they alias)
__global__ void ewise(const float* g, const float* __restrict__ big,
                      const float* __restrict__ x, float* ys, int n4)
{
    int i = blockIdx.x * blockDim.x + threadIdx.x;
    if (i >= n4) return;
    float4 gv = ((const float4*)g)[i];
    float4 bv = ((const float4*)big)[i];
    float4 xv = ((const float4*)x)[i];
    float4 r;
    r.x = gv.x * bv.x + (1.f - gv.x) * xv.x;
    r.y = gv.y * bv.y + (1.f - gv.y) * xv.y;
    r.z = gv.z * bv.z + (1.f - gv.z) * xv.z;
    r.w = gv.w * bv.w + (1.f - gv.w) * xv.w;
    ((float4*)ys)[i] = r;
}

extern "C" void kernel_launch(void* const* d_in, const int* in_sizes, int n_in,
                              void* d_out, int out_size, void* d_ws, size_t ws_size,
                              hipStream_t stream)
{
    const float* x      = (const float*)d_in[0];
    const float* W_in   = (const float*)d_in[1];
    const float* b_in   = (const float*)d_in[2];
    const float* W_gate = (const float*)d_in[3];
    const float* b_gate = (const float*)d_in[4];
    const float* Amat   = (const float*)d_in[5];
    const float* Bm     = (const float*)d_in[6];
    const float* Cm     = (const float*)d_in[7];
    const float* Dm     = (const float*)d_in[8];
    const float* W_out  = (const float*)d_in[9];
    const float* b_out  = (const float*)d_in[10];
    float* out = (float*)d_out;

    const int T = 2048, DM = 1024, DS = 256;
    const int M = 8 * T;  // 16384

    char* ws = (char*)d_ws;
    float* u   = (float*)(ws);
    float* u2  = (float*)(ws + (size_t)16 * 1024 * 1024);
    float* h   = (float*)(ws + (size_t)32 * 1024 * 1024);
    float* big = (float*)(ws + (size_t)48 * 1024 * 1024);
    float* g   = (float*)(ws + (size_t)112 * 1024 * 1024);

    dim3 blk(256);
    // u = x @ W_in + b_in
    gemm64<E_BIAS, false><<<dim3(DS / 64, M / 64), blk, 0, stream>>>(
        x, W_in, b_in, nullptr, u, M, DS, DM);
    // big = u @ D^T
    gemm64<E_NONE, true><<<dim3(DM / 64, M / 64), blk, 0, stream>>>(
        u, Dm, nullptr, nullptr, big, M, DM, DS);
    // u2 = u @ Bm
    gemm64<E_NONE, false><<<dim3(DS / 64, M / 64), blk, 0, stream>>>(
        u, Bm, nullptr, nullptr, u2, M, DS, DS);
    // g = sigmoid(x @ W_gate + b_gate)
    gemm64<E_SIG, false><<<dim3(DM / 64, M / 64), blk, 0, stream>>>(
        x, W_gate, b_gate, nullptr, g, M, DM, DM);
    // h recurrence (one block per batch)
    scan_kernel<<<8, 1024, 0, stream>>>(Amat, u2, h);
    // big += h @ C^T
    gemm64<E_ACC, true><<<dim3(DM / 64, M / 64), blk, 0, stream>>>(
        h, Cm, nullptr, nullptr, big, M, DM, DS);
    // g = g*big + (1-g)*x   (ys, in place)
    const int n4 = M * DM / 4;
    ewise<<<n4 / 256, 256, 0, stream>>>(g, big, x, g, n4);
    // out = ys @ W_out + b_out + x
    gemm64<E_BIASRES, false><<<dim3(DM / 64, M / 64), blk, 0, stream>>>(
        g, W_out, b_out, x, out, M, DM, DM);
}